// Round 14
// baseline (907.055 us; speedup 1.0000x reference)
//
#include <hip/hip_runtime.h>

#define C 256
#define NPOS 2048
#define BB 8
#define TTIME 4
#define PRM_STRIDE 132096  // w1fT 65536 | w2fT 65536 | w3T 768 | bias 256
#define FRAG_ELEMS 196608  // 8 ks * 16 mt * 3 s * 64 lane * 8 j (bf16)

typedef float f32x4 __attribute__((ext_vector_type(4)));
typedef short short8 __attribute__((ext_vector_type(8)));
typedef unsigned int u32x4 __attribute__((ext_vector_type(4)));

static __device__ __forceinline__ unsigned short f2bf(float f) {
    unsigned int u = __float_as_uint(f);
    return (unsigned short)((u + 0x7FFFu + ((u >> 16) & 1u)) >> 16);
}
static __device__ __forceinline__ float bf2f(unsigned short b) {
    return __uint_as_float(((unsigned int)b) << 16);
}
static __device__ __forceinline__ void split3(float f, unsigned short& h,
                                              unsigned short& m, unsigned short& l) {
    h = f2bf(f);
    float r1 = f - bf2f(h);
    m = f2bf(r1);
    float r2 = r1 - bf2f(m);
    l = f2bf(r2);
}
// truncation-based 3-way split of a PAIR of f32 into packed 2xbf16 words.
static __device__ __forceinline__ void tsplit_pair(float a, float b,
    unsigned int& hp, unsigned int& mp, unsigned int& lp) {
    unsigned int ua = __float_as_uint(a), ub = __float_as_uint(b);
    hp = (ua >> 16) | (ub & 0xFFFF0000u);
    float ra = a - __uint_as_float(ua & 0xFFFF0000u);
    float rb = b - __uint_as_float(ub & 0xFFFF0000u);
    unsigned int ura = __float_as_uint(ra), urb = __float_as_uint(rb);
    mp = (ura >> 16) | (urb & 0xFFFF0000u);
    float sa = ra - __uint_as_float(ura & 0xFFFF0000u);
    float sb = rb - __uint_as_float(urb & 0xFFFF0000u);
    lp = (__float_as_uint(sa) >> 16) | (__float_as_uint(sb) & 0xFFFF0000u);
}

// ---------------- PREP1: fold BN params into conv weights (f32) ----------------
__global__ __launch_bounds__(256) void prep_kern(
    const float* __restrict__ w1g, const float* __restrict__ bn1,
    const float* __restrict__ w3g, const float* __restrict__ w2g,
    const float* __restrict__ bn2, const float* __restrict__ bno,
    float* __restrict__ prm)
{
    int i = blockIdx.x;
    int tid = threadIdx.x;
    __shared__ float s1l[C], hcl[C], SGl[C];
    const float* b1 = bn1 + i * 4 * C;
    const float* b2 = bn2 + i * 4 * C;
    const float* bo = bno + i * 4 * C;
    float g1 = b1[tid], be1 = b1[C + tid], mu1 = b1[2 * C + tid], va1 = b1[3 * C + tid];
    float s1 = g1 / sqrtf(va1 + 1e-5f);
    float h1 = be1 - mu1 * s1;
    float g2 = b2[tid], be2 = b2[C + tid], mu2 = b2[2 * C + tid], va2 = b2[3 * C + tid];
    float s2 = g2 / sqrtf(va2 + 1e-5f);
    float h2 = be2 - mu2 * s2;
    float go = bo[tid], beo = bo[C + tid], muo = bo[2 * C + tid], vao = bo[3 * C + tid];
    float so = go / sqrtf(vao + 1e-5f);
    float ho = beo - muo * so;
    float SG = so * s2;
    float SH = so * h2 + ho;
    const float* w3i = w3g + i * C * 3;
    float w3s = w3i[tid * 3 + 0] + w3i[tid * 3 + 1] + w3i[tid * 3 + 2];
    s1l[tid] = s1; hcl[tid] = w3s * h1; SGl[tid] = SG;
    __syncthreads();
    float* prmi = prm + (size_t)i * PRM_STRIDE;
    const float* w1i = w1g + (size_t)i * C * C;
    const float* w2i = w2g + (size_t)i * C * C;
    for (int k = 0; k < C; ++k)
        prmi[tid * C + k] = s1l[k] * w1i[k * C + tid];
    for (int k = 0; k < C; ++k)
        prmi[65536 + tid * C + k] = SGl[k] * w2i[k * C + tid];
    for (int j = 0; j < 3; ++j)
        prmi[131072 + j * C + tid] = w3i[tid * 3 + j];
    float dot = 0.f;
    for (int k = 0; k < C; ++k)
        dot = fmaf(w2i[tid * C + k], hcl[k], dot);
    prmi[131840 + tid] = SG * dot + SH;
}

// ---------------- PREP2: build bf16x3 MFMA A-fragments ----------------
// frag layout: ((((ks*16 + mt)*3 + s)*64 + lane)*8 + j)
// lane l holds A[m = mt*16 + (l&15)][k = ks*32 + (l>>4)*8 + j]
__global__ __launch_bounds__(256) void prep2_kern(
    const float* __restrict__ prm, unsigned short* __restrict__ frags)
{
    int b = blockIdx.x;           // 12 = 6 convs x 2 matrices
    int i = b >> 1, which = b & 1;
    const float* src = prm + (size_t)i * PRM_STRIDE + which * 65536;  // wT[k*256+m]
    unsigned short* dst = frags + (size_t)b * FRAG_ELEMS;
    for (int e = threadIdx.x; e < 65536; e += 256) {
        int m = e & 255, k = e >> 8;
        float w = src[k * 256 + m];
        unsigned short h, mi, lo;
        split3(w, h, mi, lo);
        int ks = k >> 5, kin = k & 31;
        int mt = m >> 4;
        int lane = (m & 15) | (((kin >> 3) & 3) << 4);
        int j = kin & 7;
        size_t base = ((size_t)(ks * 16 + mt) * 3) * 64 * 8 + lane * 8 + j;
        dst[base] = h;
        dst[base + 512] = mi;
        dst[base + 1024] = lo;
    }
}

// ---------------- FUSED conv: y = W2f * dw3(W1f * x) + bias ----------------
// IN_MODE: 0 = STD f32 [c][pos], 1 = TRS f32 [pos][c], 2 = SPIKE bitmask
// OUT_T:   1 = transposed yT[pos][c] (LDS-staged coalesced), 0 = standard y[c][pos]
// 1024-THREAD BLOCK (16 waves), one wave per m-tile (mt = wv): per-wave acc
// shrinks to 36 (AGPR) so arch+acc fits the 128-reg budget of 4 waves/SIMD —
// 2x the wave-level parallelism of the 256-thread version (which was pinned
// at 2 waves/SIMD by 128 arch + 144 acc). Same grid, same math, bit-identical
// MFMA order per accumulator.
//   stage 1: x planes 80 cols x 64 k  @ 0/10240/20480  (30720 B, 4 sub-phases)
//   stage 2: t planes 64 cols x 64 k  @ 0/8192/16384   (24576 B, 4 sub-phases,
//            DWSPLIT by waves 4s..4s+3 only — one per SIMD)
//   epilogue: 16 pos x 256 c f32      @ 0..16384       (4 phases)
// All acc indices compile-time (rule #20). Spill tripwire: WRITE_SIZE>65536.
template<int IN_MODE, int OUT_T>
__global__ __launch_bounds__(1024) void conv_fused(
    const float* __restrict__ x, const unsigned int* __restrict__ xmask,
    float* __restrict__ y, const unsigned short* __restrict__ fragA,
    const unsigned short* __restrict__ fragB, const float* __restrict__ prmi)
{
    __shared__ __align__(16) char lds[30720];
    const int tid = threadIdx.x;
    const int lane = tid & 63, wv = tid >> 6;      // wv = mt, 0..15
    const int ctile = blockIdx.x & 31;
    const int slice = blockIdx.x >> 5;
    const int l0 = ctile * 64;
    const int lo4 = lane & 15, rg = lane >> 4;
    const int PA[6] = {0, 0, 1, 0, 2, 1};
    const int PB[6] = {0, 1, 0, 2, 0, 1};

    f32x4 acc1[5];
#pragma unroll
    for (int b = 0; b < 5; ++b) acc1[b] = (f32x4)0.f;

    const short8* Ab1 = (const short8*)fragA;

    // prefetch buffer: up to 2 units x 4 k-elements
    float LDf[8];
    unsigned int LDu[8];

#define ISSUE(sp_)                                                             \
    {                                                                          \
        _Pragma("unroll")                                                      \
        for (int it = 0; it < 2; ++it) {                                       \
            int u = it * 1024 + tid;                                           \
            if (u < 1280) {                                                    \
                int col = u % 80;                                              \
                int kq4 = u / 80;                                              \
                int gpos = l0 - 8 + col;                                       \
                bool ok = (unsigned)gpos < (unsigned)NPOS;                     \
                int k0 = (sp_) * 64 + kq4 * 4;                                 \
                if (IN_MODE == 2) {                                            \
                    const unsigned int* mg = xmask + (size_t)slice * C * 64 + (gpos >> 5); \
                    _Pragma("unroll")                                          \
                    for (int j = 0; j < 4; ++j)                                \
                        LDu[it * 4 + j] = ok ? mg[(k0 + j) * 64] : 0u;         \
                } else if (IN_MODE == 0) {                                     \
                    const float* xg = x + (size_t)slice * C * NPOS + gpos;     \
                    _Pragma("unroll")                                          \
                    for (int j = 0; j < 4; ++j)                                \
                        LDf[it * 4 + j] = ok ? xg[(size_t)(k0 + j) * NPOS] : 0.f; \
                } else {                                                       \
                    if (ok) {                                                  \
                        float4 a4 = *(const float4*)(x + ((size_t)slice * NPOS + gpos) * C + k0); \
                        LDf[it * 4 + 0] = a4.x; LDf[it * 4 + 1] = a4.y;        \
                        LDf[it * 4 + 2] = a4.z; LDf[it * 4 + 3] = a4.w;        \
                    } else {                                                   \
                        _Pragma("unroll")                                      \
                        for (int j = 0; j < 4; ++j) LDf[it * 4 + j] = 0.f;     \
                    }                                                          \
                }                                                              \
            }                                                                  \
        }                                                                      \
    }

#define SPLIT(sp_)                                                             \
    {                                                                          \
        _Pragma("unroll")                                                      \
        for (int it = 0; it < 2; ++it) {                                       \
            int u = it * 1024 + tid;                                           \
            if (u < 1280) {                                                    \
                int col = u % 80;                                              \
                int kq4 = u / 80;                                              \
                int base = col * 128 + ((((kq4 >> 1) ^ (col & 7)) & 7) << 4) + (kq4 & 1) * 8; \
                if (IN_MODE == 2) {                                            \
                    int gpos = l0 - 8 + col;                                   \
                    int bitp = gpos & 31;                                      \
                    unsigned int h01 = (((LDu[it * 4 + 0] >> bitp) & 1u) ? 0x3F80u : 0u)   \
                                     | (((LDu[it * 4 + 1] >> bitp) & 1u) ? 0x3F800000u : 0u); \
                    unsigned int h23 = (((LDu[it * 4 + 2] >> bitp) & 1u) ? 0x3F80u : 0u)   \
                                     | (((LDu[it * 4 + 3] >> bitp) & 1u) ? 0x3F800000u : 0u); \
                    *(unsigned long long*)(lds + base) =                       \
                        (unsigned long long)h01 | ((unsigned long long)h23 << 32); \
                } else {                                                       \
                    unsigned int h01, m01, l01, h23, m23, l23;                 \
                    tsplit_pair(LDf[it * 4 + 0], LDf[it * 4 + 1], h01, m01, l01); \
                    tsplit_pair(LDf[it * 4 + 2], LDf[it * 4 + 3], h23, m23, l23); \
                    *(unsigned long long*)(lds + base) =                       \
                        (unsigned long long)h01 | ((unsigned long long)h23 << 32); \
                    *(unsigned long long*)(lds + 10240 + base) =               \
                        (unsigned long long)m01 | ((unsigned long long)m23 << 32); \
                    *(unsigned long long*)(lds + 20480 + base) =               \
                        (unsigned long long)l01 | ((unsigned long long)l23 << 32); \
                }                                                              \
            }                                                                  \
        }                                                                      \
    }

    // ================= STAGE 1: u = W1f * x (4 sub-phases of 64 k) ===========
    ISSUE(0);
#pragma unroll
    for (int sp = 0; sp < 4; ++sp) {
        SPLIT(sp);
        if (sp < 3) ISSUE(sp + 1);
        __syncthreads();
#pragma unroll
        for (int ksl = 0; ksl < 2; ++ksl) {
            int ks = sp * 2 + ksl;
            int oct = ksl * 4 + rg;          // 0..7
            short8 A[3];
#pragma unroll
            for (int s = 0; s < 3; ++s)
                A[s] = Ab1[(size_t)((ks * 16 + wv) * 3 + s) * 64 + lane];
            int ba[5];
#pragma unroll
            for (int ct = 0; ct < 5; ++ct) {
                int colb = ct * 16 + lo4;
                ba[ct] = colb * 128 + (((oct ^ (colb & 7)) & 7) << 4);
            }
            if (IN_MODE == 2) {
                short8 B[5];
#pragma unroll
                for (int ct = 0; ct < 5; ++ct)
                    B[ct] = *(const short8*)(lds + ba[ct]);
                __builtin_amdgcn_s_setprio(1);
#pragma unroll
                for (int pp = 0; pp < 3; ++pp)
#pragma unroll
                    for (int ct = 0; ct < 5; ++ct)
                        acc1[ct] = __builtin_amdgcn_mfma_f32_16x16x32_bf16(
                            A[pp], B[ct], acc1[ct], 0, 0, 0);
                __builtin_amdgcn_s_setprio(0);
            } else {
                // ct groups {0,1},{2,3},{4} to cap live B regs
#pragma unroll
                for (int g = 0; g < 3; ++g) {
                    const int nct = (g < 2) ? 2 : 1;
                    const int c0g = g * 2;
                    short8 B[2][3];
#pragma unroll
                    for (int cc = 0; cc < nct; ++cc) {
                        B[cc][0] = *(const short8*)(lds + ba[c0g + cc]);
                        B[cc][1] = *(const short8*)(lds + 10240 + ba[c0g + cc]);
                        B[cc][2] = *(const short8*)(lds + 20480 + ba[c0g + cc]);
                    }
                    __builtin_amdgcn_s_setprio(1);
#pragma unroll
                    for (int pp = 0; pp < 6; ++pp)
#pragma unroll
                        for (int cc = 0; cc < nct; ++cc)
                            acc1[c0g + cc] = __builtin_amdgcn_mfma_f32_16x16x32_bf16(
                                A[PA[pp]], B[cc][PB[pp]], acc1[c0g + cc], 0, 0, 0);
                    __builtin_amdgcn_s_setprio(0);
                }
            }
        }
        __syncthreads();
    }

    // ================= STAGE 2: y = W2f * dw3(u), 4 sub-phases of 64 k' ======
    const float* w3p = prmi + 131072;
    const short8* Ab2 = (const short8*)fragB;
    f32x4 acc2[4];
#pragma unroll
    for (int b = 0; b < 4; ++b) acc2[b] = (f32x4)0.f;

#pragma unroll
    for (int s = 0; s < 4; ++s) {
        // ---- DWSPLIT: waves 4s..4s+3 (one per SIMD) write k' [64s,64s+64) ----
        if ((wv >> 2) == s) {
            int m0b = wv << 4;
            float w3a[4], w3b[4], w3c[4];
#pragma unroll
            for (int r = 0; r < 4; ++r) {
                int m = m0b + rg * 4 + r;
                w3a[r] = w3p[m]; w3b[r] = w3p[256 + m]; w3c[r] = w3p[512 + m];
            }
            int k0 = ((wv & 3) << 4) + rg * 4;   // within [0,64)
#pragma unroll
            for (int ct = 0; ct < 5; ++ct) {
                int sc = ct * 16 + lo4;
                float tv[4];
#pragma unroll
                for (int r = 0; r < 4; ++r) {
                    float cur = acc1[ct][r];
                    float prevv = acc1[ct > 0 ? ct - 1 : 0][r];
                    float nextv = acc1[ct < 4 ? ct + 1 : 4][r];
                    float sL  = __shfl(cur, lane - 1);
                    float sL2 = __shfl(prevv, lane + 15);
                    float sR  = __shfl(cur, lane + 1);
                    float sR2 = __shfl(nextv, lane - 15);
                    float uL = lo4 ? sL : sL2;
                    float uR = (lo4 == 15) ? sR2 : sR;
                    tv[r] = w3a[r] * uL + w3b[r] * cur + w3c[r] * uR;
                }
                if (sc >= 8 && sc < 72) {
                    int oc = sc - 8;
                    int base = oc * 128 + ((((k0 >> 3) ^ (oc & 7)) & 7) << 4) + (k0 & 7) * 2;
                    unsigned int h01, m01, l01, h23, m23, l23;
                    tsplit_pair(tv[0], tv[1], h01, m01, l01);
                    tsplit_pair(tv[2], tv[3], h23, m23, l23);
                    *(unsigned long long*)(lds + base) =
                        (unsigned long long)h01 | ((unsigned long long)h23 << 32);
                    *(unsigned long long*)(lds + 8192 + base) =
                        (unsigned long long)m01 | ((unsigned long long)m23 << 32);
                    *(unsigned long long*)(lds + 16384 + base) =
                        (unsigned long long)l01 | ((unsigned long long)l23 << 32);
                }
            }
        }
        __syncthreads();
        // ---- MFMA: ks = 2s, 2s+1 over 4 ct (pairs) ----
#pragma unroll
        for (int ksl = 0; ksl < 2; ++ksl) {
            int ks = s * 2 + ksl;
            int chunk = ksl * 4 + rg;        // 0..7
            short8 A[3];
#pragma unroll
            for (int ss = 0; ss < 3; ++ss)
                A[ss] = Ab2[(size_t)((ks * 16 + wv) * 3 + ss) * 64 + lane];
#pragma unroll
            for (int g = 0; g < 2; ++g) {
                const int c0g = g * 2;
                short8 B[2][3];
#pragma unroll
                for (int cc = 0; cc < 2; ++cc) {
                    int oc = (c0g + cc) * 16 + lo4;
                    int ba = oc * 128 + (((chunk ^ (oc & 7)) & 7) << 4);
                    B[cc][0] = *(const short8*)(lds + ba);
                    B[cc][1] = *(const short8*)(lds + 8192 + ba);
                    B[cc][2] = *(const short8*)(lds + 16384 + ba);
                }
                __builtin_amdgcn_s_setprio(1);
#pragma unroll
                for (int pp = 0; pp < 6; ++pp)
#pragma unroll
                    for (int cc = 0; cc < 2; ++cc)
                        acc2[c0g + cc] = __builtin_amdgcn_mfma_f32_16x16x32_bf16(
                            A[PA[pp]], B[cc][PB[pp]], acc2[c0g + cc], 0, 0, 0);
                __builtin_amdgcn_s_setprio(0);
            }
        }
        __syncthreads();
    }

    // ================= epilogue =================
    const float* bs = prmi + 131840;
    float* yS = y + (size_t)slice * NPOS * C;
    const int m0 = (wv << 4) + rg * 4;
    if (OUT_T) {
        // LDS-staged transpose: 4 phases of 16 pos x 256 ch (16 KB), then
        // fully-coalesced row stores (one f32x4 per thread per phase).
        const int chunk = (wv << 2) + rg;    // m0/4, 0..63
#pragma unroll
        for (int ph = 0; ph < 4; ++ph) {
            if (ph) __syncthreads();
            {
                int cl = lo4;                // 0..15
                f32x4 o;
#pragma unroll
                for (int r = 0; r < 4; ++r) o[r] = acc2[ph][r] + bs[m0 + r];
                *(f32x4*)(lds + cl * 1024 + ((chunk ^ (cl & 7)) << 4)) = o;
            }
            __syncthreads();
            {
                int cl = tid >> 6, cchunk = tid & 63;
                f32x4 o = *(const f32x4*)(lds + cl * 1024 + ((cchunk ^ (cl & 7)) << 4));
                int pos = l0 + ph * 16 + cl;
                *(f32x4*)(yS + (size_t)pos * C + cchunk * 4) = o;
            }
        }
    } else {
#pragma unroll
        for (int ct = 0; ct < 4; ++ct) {
            int pos = l0 + ct * 16 + lo4;
#pragma unroll
            for (int r = 0; r < 4; ++r)
                yS[(size_t)(m0 + r) * NPOS + pos] = acc2[ct][r] + bs[m0 + r];
        }
    }
#undef ISSUE
#undef SPLIT
}

// ---------------- LIF + bitpack over T timesteps (reads yT[pos][c]) ----------------
__global__ __launch_bounds__(256) void lif_kern(
    const float* __restrict__ yT, unsigned int* __restrict__ mask, float vth)
{
    int g = blockIdx.x * 256 + threadIdx.x;   // 131072 = 8b x 64w x 256ch
    int ch = g & 255;
    int w = (g >> 8) & 63;
    int b = g >> 14;
    float v[32];
#pragma unroll
    for (int j = 0; j < 32; ++j) v[j] = 0.f;
    for (int t = 0; t < TTIME; ++t) {
        int slice = t * BB + b;
        const float* yr = yT + ((size_t)slice * NPOS + w * 32) * C + ch;
        unsigned int mw = 0;
#pragma unroll
        for (int j = 0; j < 32; ++j) {
            float yy = yr[(size_t)j * C];
            float vn = v[j] + (yy - v[j]) * 0.5f;
            int sp = (vn - vth) >= 0.0f;
            mw |= ((unsigned int)sp) << j;
            v[j] = sp ? 0.f : vn;
        }
        mask[((size_t)slice * C + ch) * 64 + w] = mw;
    }
}

// ---------------- kv popcount ----------------
__global__ __launch_bounds__(256) void kv_kern(
    const unsigned int* __restrict__ km_g, const unsigned int* __restrict__ vm_g,
    int* __restrict__ kv_g)
{
    int blk = blockIdx.x;
    int h = blk & 7;
    int tb = blk >> 3;
    __shared__ unsigned int km[32][65], vm[32][65];
    int tid = threadIdx.x;
#pragma unroll
    for (int i = 0; i < 8; ++i) {
        int idx = i * 256 + tid;
        int d = idx >> 6, w = idx & 63;
        size_t rb = ((size_t)tb * C + h * 32 + d) * 64 + w;
        km[d][w] = km_g[rb];
        vm[d][w] = vm_g[rb];
    }
    __syncthreads();
#pragma unroll
    for (int k = 0; k < 4; ++k) {
        int p = k * 256 + tid;
        int d = p >> 5, e = p & 31;
        int s = 0;
#pragma unroll
        for (int w = 0; w < 64; ++w)
            s += __popc(km[d][w] & vm[e][w]);
        kv_g[(size_t)blk * 1024 + p] = s;
    }
}

// ---------------- attention + attn-LIF -> bit mask ----------------
__global__ __launch_bounds__(256) void attn_kern(
    const unsigned int* __restrict__ qm_g, const int* __restrict__ kv_g,
    unsigned int* __restrict__ amask)
{
    int blk = blockIdx.x;
    int chunk = blk & 7;
    int bh = blk >> 3;
    int h = bh & 7, b = bh >> 3;
    int tid = threadIdx.x;
    __shared__ int kvs[1024];
    __shared__ unsigned int qw[32][8];
    float v[32];
#pragma unroll
    for (int e = 0; e < 32; ++e) v[e] = 0.f;
    for (int t = 0; t < TTIME; ++t) {
        int tb = t * BB + b;
        __syncthreads();
#pragma unroll
        for (int k = 0; k < 4; ++k)
            kvs[k * 256 + tid] = kv_g[((size_t)tb * 8 + h) * 1024 + k * 256 + tid];
        {
            int d = tid >> 3, wi = tid & 7;
            qw[d][wi] = qm_g[((size_t)tb * C + h * 32 + d) * 64 + chunk * 8 + wi];
        }
        __syncthreads();
        int a[32];
#pragma unroll
        for (int e = 0; e < 32; ++e) a[e] = 0;
        int wsel = tid >> 5, bitp = tid & 31;
        for (int d = 0; d < 32; ++d) {
            if ((qw[d][wsel] >> bitp) & 1u) {
                const int* kr = &kvs[d * 32];
#pragma unroll
                for (int e = 0; e < 32; ++e) a[e] += kr[e];
            }
        }
#pragma unroll
        for (int e = 0; e < 32; ++e) {
            float f = (float)a[e] * 0.125f;
            v[e] = v[e] + (f - v[e]) * 0.5f;
            int sp = (v[e] - 0.5f) >= 0.0f;
            unsigned long long bb = __ballot(sp);
            if ((tid & 63) == 0) {
                int ch = h * 32 + e;
                unsigned long long* dst = (unsigned long long*)amask
                    + ((size_t)tb * C + ch) * 32 + chunk * 4 + (tid >> 6);
                *dst = bb;
            }
            if (sp) v[e] = 0.f;
        }
    }
}

extern "C" void kernel_launch(void* const* d_in, const int* in_sizes, int n_in,
                              void* d_out, int out_size, void* d_ws, size_t ws_size,
                              hipStream_t stream) {
    const float* q   = (const float*)d_in[0];
    const float* k_  = (const float*)d_in[1];
    const float* w1g = (const float*)d_in[2];
    const float* bn1 = (const float*)d_in[3];
    const float* w3g = (const float*)d_in[4];
    const float* w2g = (const float*)d_in[5];
    const float* bn2 = (const float*)d_in[6];
    const float* bno = (const float*)d_in[7];

    float* prm = (float*)d_ws;                                        // 792576 f32
    unsigned short* frags = (unsigned short*)(prm + 6 * PRM_STRIDE);  // 12*196608 bf16
    float* bufA = (float*)(frags + 12 * FRAG_ELEMS);                  // 16777216 f32
    float* bufB = bufA + 16777216;                                    // 16777216 f32
    unsigned int* qmask = (unsigned int*)(bufB + 16777216);           // 524288 u32 each
    unsigned int* kmask = qmask + 524288;
    unsigned int* vmask = kmask + 524288;
    int* kvb = (int*)(vmask + 524288);                                // 262144 i32
    unsigned int* amask = (unsigned int*)(kvb + 262144);              // 524288 u32

    prep_kern<<<6, 256, 0, stream>>>(w1g, bn1, w3g, w2g, bn2, bno, prm);
    prep2_kern<<<12, 256, 0, stream>>>(prm, frags);

#define FRAG(i, which) (frags + (size_t)((i) * 2 + (which)) * FRAG_ELEMS)
#define PRMI(i) (prm + (size_t)(i) * PRM_STRIDE)

    // q branch: conv0 -> LIF -> qmask
    conv_fused<0, 1><<<1024, 1024, 0, stream>>>(q, nullptr, bufA, FRAG(0, 0), FRAG(0, 1), PRMI(0));
    lif_kern<<<512, 256, 0, stream>>>(bufA, qmask, 1.0f);
    // k branch: conv1 -> conv2 -> LIF -> kmask
    conv_fused<0, 1><<<1024, 1024, 0, stream>>>(k_, nullptr, bufA, FRAG(1, 0), FRAG(1, 1), PRMI(1));
    conv_fused<1, 1><<<1024, 1024, 0, stream>>>(bufA, nullptr, bufB, FRAG(2, 0), FRAG(2, 1), PRMI(2));
    lif_kern<<<512, 256, 0, stream>>>(bufB, kmask, 1.0f);
    // v branch: conv3 -> conv4 -> LIF -> vmask
    conv_fused<0, 1><<<1024, 1024, 0, stream>>>(k_, nullptr, bufA, FRAG(3, 0), FRAG(3, 1), PRMI(3));
    conv_fused<1, 1><<<1024, 1024, 0, stream>>>(bufA, nullptr, bufB, FRAG(4, 0), FRAG(4, 1), PRMI(4));
    lif_kern<<<512, 256, 0, stream>>>(bufB, vmask, 1.0f);

    kv_kern<<<256, 256, 0, stream>>>(kmask, vmask, kvb);
    attn_kern<<<512, 256, 0, stream>>>(qmask, kvb, amask);

    // final conv5: spike-input, standard-layout output
    conv_fused<2, 0><<<1024, 1024, 0, stream>>>(nullptr, amask, (float*)d_out, FRAG(5, 0), FRAG(5, 1), PRMI(5));
}

// Round 15
// 802.266 us; speedup vs baseline: 1.1306x; 1.1306x over previous
//
#include <hip/hip_runtime.h>

#define C 256
#define NPOS 2048
#define BB 8
#define TTIME 4
#define PRM_STRIDE 132096  // w1fT 65536 | w2fT 65536 | w3T 768 | bias 256
#define FRAG_ELEMS 196608  // 8 ks * 16 mt * 3 s * 64 lane * 8 j (bf16)

typedef float f32x4 __attribute__((ext_vector_type(4)));
typedef short short8 __attribute__((ext_vector_type(8)));
typedef unsigned int u32x4 __attribute__((ext_vector_type(4)));

struct CArgs {
    const float* x;
    const unsigned int* xmask;
    float* y;
    const unsigned short* fA;
    const unsigned short* fB;
    const float* prm;
};

static __device__ __forceinline__ unsigned short f2bf(float f) {
    unsigned int u = __float_as_uint(f);
    return (unsigned short)((u + 0x7FFFu + ((u >> 16) & 1u)) >> 16);
}
static __device__ __forceinline__ float bf2f(unsigned short b) {
    return __uint_as_float(((unsigned int)b) << 16);
}
static __device__ __forceinline__ void split3(float f, unsigned short& h,
                                              unsigned short& m, unsigned short& l) {
    h = f2bf(f);
    float r1 = f - bf2f(h);
    m = f2bf(r1);
    float r2 = r1 - bf2f(m);
    l = f2bf(r2);
}
// truncation-based 3-way split of a PAIR of f32 into packed 2xbf16 words.
static __device__ __forceinline__ void tsplit_pair(float a, float b,
    unsigned int& hp, unsigned int& mp, unsigned int& lp) {
    unsigned int ua = __float_as_uint(a), ub = __float_as_uint(b);
    hp = (ua >> 16) | (ub & 0xFFFF0000u);
    float ra = a - __uint_as_float(ua & 0xFFFF0000u);
    float rb = b - __uint_as_float(ub & 0xFFFF0000u);
    unsigned int ura = __float_as_uint(ra), urb = __float_as_uint(rb);
    mp = (ura >> 16) | (urb & 0xFFFF0000u);
    float sa = ra - __uint_as_float(ura & 0xFFFF0000u);
    float sb = rb - __uint_as_float(urb & 0xFFFF0000u);
    lp = (__float_as_uint(sa) >> 16) | (__float_as_uint(sb) & 0xFFFF0000u);
}

// ---------------- PREP1: fold BN params into conv weights (f32) ----------------
__global__ __launch_bounds__(256) void prep_kern(
    const float* __restrict__ w1g, const float* __restrict__ bn1,
    const float* __restrict__ w3g, const float* __restrict__ w2g,
    const float* __restrict__ bn2, const float* __restrict__ bno,
    float* __restrict__ prm)
{
    int i = blockIdx.x;
    int tid = threadIdx.x;
    __shared__ float s1l[C], hcl[C], SGl[C];
    const float* b1 = bn1 + i * 4 * C;
    const float* b2 = bn2 + i * 4 * C;
    const float* bo = bno + i * 4 * C;
    float g1 = b1[tid], be1 = b1[C + tid], mu1 = b1[2 * C + tid], va1 = b1[3 * C + tid];
    float s1 = g1 / sqrtf(va1 + 1e-5f);
    float h1 = be1 - mu1 * s1;
    float g2 = b2[tid], be2 = b2[C + tid], mu2 = b2[2 * C + tid], va2 = b2[3 * C + tid];
    float s2 = g2 / sqrtf(va2 + 1e-5f);
    float h2 = be2 - mu2 * s2;
    float go = bo[tid], beo = bo[C + tid], muo = bo[2 * C + tid], vao = bo[3 * C + tid];
    float so = go / sqrtf(vao + 1e-5f);
    float ho = beo - muo * so;
    float SG = so * s2;
    float SH = so * h2 + ho;
    const float* w3i = w3g + i * C * 3;
    float w3s = w3i[tid * 3 + 0] + w3i[tid * 3 + 1] + w3i[tid * 3 + 2];
    s1l[tid] = s1; hcl[tid] = w3s * h1; SGl[tid] = SG;
    __syncthreads();
    float* prmi = prm + (size_t)i * PRM_STRIDE;
    const float* w1i = w1g + (size_t)i * C * C;
    const float* w2i = w2g + (size_t)i * C * C;
    for (int k = 0; k < C; ++k)
        prmi[tid * C + k] = s1l[k] * w1i[k * C + tid];
    for (int k = 0; k < C; ++k)
        prmi[65536 + tid * C + k] = SGl[k] * w2i[k * C + tid];
    for (int j = 0; j < 3; ++j)
        prmi[131072 + j * C + tid] = w3i[tid * 3 + j];
    float dot = 0.f;
    for (int k = 0; k < C; ++k)
        dot = fmaf(w2i[tid * C + k], hcl[k], dot);
    prmi[131840 + tid] = SG * dot + SH;
}

// ---------------- PREP2: build bf16x3 MFMA A-fragments ----------------
// frag layout: ((((ks*16 + mt)*3 + s)*64 + lane)*8 + j)
// lane l holds A[m = mt*16 + (l&15)][k = ks*32 + (l>>4)*8 + j]
__global__ __launch_bounds__(256) void prep2_kern(
    const float* __restrict__ prm, unsigned short* __restrict__ frags)
{
    int b = blockIdx.x;           // 12 = 6 convs x 2 matrices
    int i = b >> 1, which = b & 1;
    const float* src = prm + (size_t)i * PRM_STRIDE + which * 65536;  // wT[k*256+m]
    unsigned short* dst = frags + (size_t)b * FRAG_ELEMS;
    for (int e = threadIdx.x; e < 65536; e += 256) {
        int m = e & 255, k = e >> 8;
        float w = src[k * 256 + m];
        unsigned short h, mi, lo;
        split3(w, h, mi, lo);
        int ks = k >> 5, kin = k & 31;
        int mt = m >> 4;
        int lane = (m & 15) | (((kin >> 3) & 3) << 4);
        int j = kin & 7;
        size_t base = ((size_t)(ks * 16 + mt) * 3) * 64 * 8 + lane * 8 + j;
        dst[base] = h;
        dst[base + 512] = mi;
        dst[base + 1024] = lo;
    }
}

// ---------------- FUSED conv: y = W2f * dw3(W1f * x) + bias ----------------
// IN_MODE: 0 = STD f32 [c][pos], 1 = TRS f32 [pos][c], 2 = SPIKE bitmask
// OUT_T:   1 = transposed yT[pos][c] (LDS-staged coalesced), 0 = standard y[c][pos]
// NB: number of independent conv branches in this launch (grid = NB*1024);
//     branch = blockIdx.x >> 10 selects its CArgs (uniform, SGPR).
// Structure = R13 (best measured): 4 sub-phase both stages, 30720 B LDS,
// (256,2) bounds, tsplit staging.
//   stage 1: x planes 80 cols x 64 k  @ 0/10240/20480  (30720 B, 4 sub-phases)
//   stage 2: t planes 64 cols x 64 k  @ 0/8192/16384   (24576 B, 4 sub-phases)
//   epilogue: 16 pos x 256 c f32      @ 0..16384       (4 phases)
// All acc indices compile-time (rule #20). Spill tripwire: WRITE_SIZE.
template<int IN_MODE, int OUT_T, int NB>
__global__ __launch_bounds__(256, 2) void conv_fused(CArgs a0, CArgs a1, CArgs a2)
{
    __shared__ __align__(16) char lds[30720];
    const int tid = threadIdx.x;
    const int lane = tid & 63, wv = tid >> 6;
    const int ctile = blockIdx.x & 31;
    const int slice = (blockIdx.x >> 5) & 31;
    const int branch = blockIdx.x >> 10;
    CArgs a = a0;
    if (NB > 1 && branch == 1) a = a1;
    if (NB > 2 && branch == 2) a = a2;
    const float* __restrict__ x = a.x;
    const unsigned int* __restrict__ xmask = a.xmask;
    float* __restrict__ y = a.y;
    const unsigned short* __restrict__ fragA = a.fA;
    const unsigned short* __restrict__ fragB = a.fB;
    const float* __restrict__ prmi = a.prm;

    const int l0 = ctile * 64;
    const int lo4 = lane & 15, rg = lane >> 4;
    const int PA[6] = {0, 0, 1, 0, 2, 1};
    const int PB[6] = {0, 1, 0, 2, 0, 1};

    int mt[4];
#pragma unroll
    for (int rt = 0; rt < 4; ++rt) mt[rt] = wv + 4 * rt;

    f32x4 acc1[4][5];
#pragma unroll
    for (int aa = 0; aa < 4; ++aa)
#pragma unroll
        for (int b = 0; b < 5; ++b) acc1[aa][b] = (f32x4)0.f;

    const short8* Ab1 = (const short8*)fragA;

    // prefetch buffer: 5 units x 4 k-elements
    float LDf[20];
    unsigned int LDu[20];

#define ISSUE(sp_)                                                             \
    {                                                                          \
        _Pragma("unroll")                                                      \
        for (int it = 0; it < 5; ++it) {                                       \
            int u = it * 256 + tid;                                            \
            int col = u % 80;                                                  \
            int kq4 = u / 80;                                                  \
            int gpos = l0 - 8 + col;                                           \
            bool ok = (unsigned)gpos < (unsigned)NPOS;                         \
            int k0 = (sp_) * 64 + kq4 * 4;                                     \
            if (IN_MODE == 2) {                                                \
                const unsigned int* mg = xmask + (size_t)slice * C * 64 + (gpos >> 5); \
                _Pragma("unroll")                                              \
                for (int j = 0; j < 4; ++j)                                    \
                    LDu[it * 4 + j] = ok ? mg[(k0 + j) * 64] : 0u;             \
            } else if (IN_MODE == 0) {                                         \
                const float* xg = x + (size_t)slice * C * NPOS + gpos;         \
                _Pragma("unroll")                                              \
                for (int j = 0; j < 4; ++j)                                    \
                    LDf[it * 4 + j] = ok ? xg[(size_t)(k0 + j) * NPOS] : 0.f;  \
            } else {                                                           \
                if (ok) {                                                      \
                    float4 a4 = *(const float4*)(x + ((size_t)slice * NPOS + gpos) * C + k0); \
                    LDf[it * 4 + 0] = a4.x; LDf[it * 4 + 1] = a4.y;            \
                    LDf[it * 4 + 2] = a4.z; LDf[it * 4 + 3] = a4.w;            \
                } else {                                                       \
                    _Pragma("unroll")                                          \
                    for (int j = 0; j < 4; ++j) LDf[it * 4 + j] = 0.f;         \
                }                                                              \
            }                                                                  \
        }                                                                      \
    }

#define SPLIT(sp_)                                                             \
    {                                                                          \
        _Pragma("unroll")                                                      \
        for (int it = 0; it < 5; ++it) {                                       \
            int u = it * 256 + tid;                                            \
            int col = u % 80;                                                  \
            int kq4 = u / 80;                                                  \
            int base = col * 128 + ((((kq4 >> 1) ^ (col & 7)) & 7) << 4) + (kq4 & 1) * 8; \
            if (IN_MODE == 2) {                                                \
                int gpos = l0 - 8 + col;                                       \
                int bitp = gpos & 31;                                          \
                unsigned int h01 = (((LDu[it * 4 + 0] >> bitp) & 1u) ? 0x3F80u : 0u)   \
                                 | (((LDu[it * 4 + 1] >> bitp) & 1u) ? 0x3F800000u : 0u); \
                unsigned int h23 = (((LDu[it * 4 + 2] >> bitp) & 1u) ? 0x3F80u : 0u)   \
                                 | (((LDu[it * 4 + 3] >> bitp) & 1u) ? 0x3F800000u : 0u); \
                *(unsigned long long*)(lds + base) =                           \
                    (unsigned long long)h01 | ((unsigned long long)h23 << 32); \
            } else {                                                           \
                unsigned int h01, m01, l01, h23, m23, l23;                     \
                tsplit_pair(LDf[it * 4 + 0], LDf[it * 4 + 1], h01, m01, l01);  \
                tsplit_pair(LDf[it * 4 + 2], LDf[it * 4 + 3], h23, m23, l23);  \
                *(unsigned long long*)(lds + base) =                           \
                    (unsigned long long)h01 | ((unsigned long long)h23 << 32); \
                *(unsigned long long*)(lds + 10240 + base) =                   \
                    (unsigned long long)m01 | ((unsigned long long)m23 << 32); \
                *(unsigned long long*)(lds + 20480 + base) =                   \
                    (unsigned long long)l01 | ((unsigned long long)l23 << 32); \
            }                                                                  \
        }                                                                      \
    }

    // ================= STAGE 1: u = W1f * x (4 pipelined 64-k sub-phases) ====
    ISSUE(0);
#pragma unroll
    for (int sp = 0; sp < 4; ++sp) {
        SPLIT(sp);
        if (sp < 3) ISSUE(sp + 1);
        __syncthreads();
#pragma unroll
        for (int ksl = 0; ksl < 2; ++ksl) {
            int ks = sp * 2 + ksl;
            int oct = ksl * 4 + rg;          // 0..7
            short8 A[4][3];
#pragma unroll
            for (int rt = 0; rt < 4; ++rt)
#pragma unroll
                for (int s = 0; s < 3; ++s)
                    A[rt][s] = Ab1[(size_t)((ks * 16 + mt[rt]) * 3 + s) * 64 + lane];
            int ba[5];
#pragma unroll
            for (int ct = 0; ct < 5; ++ct) {
                int colb = ct * 16 + lo4;
                ba[ct] = colb * 128 + (((oct ^ (colb & 7)) & 7) << 4);
            }
            if (IN_MODE == 2) {
                short8 B[5];
#pragma unroll
                for (int ct = 0; ct < 5; ++ct)
                    B[ct] = *(const short8*)(lds + ba[ct]);
                __builtin_amdgcn_s_setprio(1);
#pragma unroll
                for (int pp = 0; pp < 3; ++pp)
#pragma unroll
                    for (int rt = 0; rt < 4; ++rt)
#pragma unroll
                        for (int ct = 0; ct < 5; ++ct)
                            acc1[rt][ct] = __builtin_amdgcn_mfma_f32_16x16x32_bf16(
                                A[rt][pp], B[ct], acc1[rt][ct], 0, 0, 0);
                __builtin_amdgcn_s_setprio(0);
            } else {
                short8 B[5][3];
#pragma unroll
                for (int ct = 0; ct < 5; ++ct) {
                    B[ct][0] = *(const short8*)(lds + ba[ct]);
                    B[ct][1] = *(const short8*)(lds + 10240 + ba[ct]);
                    B[ct][2] = *(const short8*)(lds + 20480 + ba[ct]);
                }
                __builtin_amdgcn_s_setprio(1);
#pragma unroll
                for (int pp = 0; pp < 6; ++pp)
#pragma unroll
                    for (int rt = 0; rt < 4; ++rt)
#pragma unroll
                        for (int ct = 0; ct < 5; ++ct)
                            acc1[rt][ct] = __builtin_amdgcn_mfma_f32_16x16x32_bf16(
                                A[rt][PA[pp]], B[ct][PB[pp]], acc1[rt][ct], 0, 0, 0);
                __builtin_amdgcn_s_setprio(0);
            }
        }
        __syncthreads();
    }

    // ================= STAGE 2: y = W2f * dw3(u), 4 sub-phases of 64 k' ======
    const float* w3p = prmi + 131072;
    const short8* Ab2 = (const short8*)fragB;
    f32x4 acc2[4][4];
#pragma unroll
    for (int aa = 0; aa < 4; ++aa)
#pragma unroll
        for (int b = 0; b < 4; ++b) acc2[aa][b] = (f32x4)0.f;

#pragma unroll
    for (int s = 0; s < 4; ++s) {
        // ---- depthwise (register shuffles) + trunc-split + t-plane write: rt = s ----
        {
            const int rt = s;                // compile-time after unroll
            int RTB = mt[rt] << 4;           // (wv + 4s)*16 -> k' in [64s,64s+64)
            float w3a[4], w3b[4], w3c[4];
#pragma unroll
            for (int r = 0; r < 4; ++r) {
                int m = RTB + rg * 4 + r;
                w3a[r] = w3p[m]; w3b[r] = w3p[256 + m]; w3c[r] = w3p[512 + m];
            }
            int k0 = (RTB & 63) + rg * 4;    // wv*16 + rg*4, within [0,64)
#pragma unroll
            for (int ct = 0; ct < 5; ++ct) {
                int sc = ct * 16 + lo4;
                float tv[4];
#pragma unroll
                for (int r = 0; r < 4; ++r) {
                    float cur = acc1[rt][ct][r];
                    float prevv = acc1[rt][ct > 0 ? ct - 1 : 0][r];
                    float nextv = acc1[rt][ct < 4 ? ct + 1 : 4][r];
                    float sL  = __shfl(cur, lane - 1);
                    float sL2 = __shfl(prevv, lane + 15);
                    float sR  = __shfl(cur, lane + 1);
                    float sR2 = __shfl(nextv, lane - 15);
                    float uL = lo4 ? sL : sL2;
                    float uR = (lo4 == 15) ? sR2 : sR;
                    tv[r] = w3a[r] * uL + w3b[r] * cur + w3c[r] * uR;
                }
                if (sc >= 8 && sc < 72) {
                    int oc = sc - 8;
                    int base = oc * 128 + ((((k0 >> 3) ^ (oc & 7)) & 7) << 4) + (k0 & 7) * 2;
                    unsigned int h01, m01, l01, h23, m23, l23;
                    tsplit_pair(tv[0], tv[1], h01, m01, l01);
                    tsplit_pair(tv[2], tv[3], h23, m23, l23);
                    *(unsigned long long*)(lds + base) =
                        (unsigned long long)h01 | ((unsigned long long)h23 << 32);
                    *(unsigned long long*)(lds + 8192 + base) =
                        (unsigned long long)m01 | ((unsigned long long)m23 << 32);
                    *(unsigned long long*)(lds + 16384 + base) =
                        (unsigned long long)l01 | ((unsigned long long)l23 << 32);
                }
            }
        }
        __syncthreads();
        // ---- MFMA: ks = 2s, 2s+1 over all rt, ct ----
#pragma unroll
        for (int ksl = 0; ksl < 2; ++ksl) {
            int ks = s * 2 + ksl;
            int chunk = ksl * 4 + rg;        // 0..7
            short8 A[4][3];
#pragma unroll
            for (int rt = 0; rt < 4; ++rt)
#pragma unroll
                for (int ss = 0; ss < 3; ++ss)
                    A[rt][ss] = Ab2[(size_t)((ks * 16 + mt[rt]) * 3 + ss) * 64 + lane];
            short8 B[4][3];
#pragma unroll
            for (int ct = 0; ct < 4; ++ct) {
                int oc = ct * 16 + lo4;
                int ba = oc * 128 + (((chunk ^ (oc & 7)) & 7) << 4);
                B[ct][0] = *(const short8*)(lds + ba);
                B[ct][1] = *(const short8*)(lds + 8192 + ba);
                B[ct][2] = *(const short8*)(lds + 16384 + ba);
            }
            __builtin_amdgcn_s_setprio(1);
#pragma unroll
            for (int pp = 0; pp < 6; ++pp)
#pragma unroll
                for (int rt = 0; rt < 4; ++rt)
#pragma unroll
                    for (int ct = 0; ct < 4; ++ct)
                        acc2[rt][ct] = __builtin_amdgcn_mfma_f32_16x16x32_bf16(
                            A[rt][PA[pp]], B[ct][PB[pp]], acc2[rt][ct], 0, 0, 0);
            __builtin_amdgcn_s_setprio(0);
        }
        __syncthreads();
    }

    // ================= epilogue =================
    const float* bs = prmi + 131840;
    float* yS = y + (size_t)slice * NPOS * C;
    if (OUT_T) {
        // LDS-staged transpose: 4 phases of 16 pos x 256 ch (16 KB), then
        // fully-coalesced 1KB-per-wave row stores.
#pragma unroll
        for (int ph = 0; ph < 4; ++ph) {
            if (ph) __syncthreads();
#pragma unroll
            for (int rt = 0; rt < 4; ++rt) {
                int m0 = (mt[rt] << 4) + rg * 4;
                int chunk = (mt[rt] << 2) + rg;       // m0/4, 0..63
                int cl = lo4;                         // 0..15
                f32x4 o;
#pragma unroll
                for (int r = 0; r < 4; ++r) o[r] = acc2[rt][ph][r] + bs[m0 + r];
                *(f32x4*)(lds + cl * 1024 + ((chunk ^ (cl & 7)) << 4)) = o;
            }
            __syncthreads();
#pragma unroll
            for (int i = 0; i < 4; ++i) {
                int u = i * 256 + tid;                // 1024 units of 16B
                int cl = u >> 6, cchunk = u & 63;
                f32x4 o = *(const f32x4*)(lds + cl * 1024 + ((cchunk ^ (cl & 7)) << 4));
                int pos = l0 + ph * 16 + cl;
                *(f32x4*)(yS + (size_t)pos * C + cchunk * 4) = o;
            }
        }
    } else {
#pragma unroll
        for (int rt = 0; rt < 4; ++rt) {
            int m0 = (mt[rt] << 4) + rg * 4;
#pragma unroll
            for (int ct = 0; ct < 4; ++ct) {
                int pos = l0 + ct * 16 + lo4;
#pragma unroll
                for (int r = 0; r < 4; ++r)
                    yS[(size_t)(m0 + r) * NPOS + pos] = acc2[rt][ct][r] + bs[m0 + r];
            }
        }
    }
#undef ISSUE
#undef SPLIT
}

// ---------------- LIF + bitpack over T timesteps (reads yT[pos][c]) ----------------
__global__ __launch_bounds__(256) void lif_kern(
    const float* __restrict__ yT, unsigned int* __restrict__ mask, float vth)
{
    int g = blockIdx.x * 256 + threadIdx.x;   // 131072 = 8b x 64w x 256ch
    int ch = g & 255;
    int w = (g >> 8) & 63;
    int b = g >> 14;
    float v[32];
#pragma unroll
    for (int j = 0; j < 32; ++j) v[j] = 0.f;
    for (int t = 0; t < TTIME; ++t) {
        int slice = t * BB + b;
        const float* yr = yT + ((size_t)slice * NPOS + w * 32) * C + ch;
        unsigned int mw = 0;
#pragma unroll
        for (int j = 0; j < 32; ++j) {
            float yy = yr[(size_t)j * C];
            float vn = v[j] + (yy - v[j]) * 0.5f;
            int sp = (vn - vth) >= 0.0f;
            mw |= ((unsigned int)sp) << j;
            v[j] = sp ? 0.f : vn;
        }
        mask[((size_t)slice * C + ch) * 64 + w] = mw;
    }
}

// ---------------- dual-LIF (two independent tensors in one launch) ----------------
__global__ __launch_bounds__(256) void lif2_kern(
    const float* __restrict__ y0, unsigned int* __restrict__ m0,
    const float* __restrict__ y1, unsigned int* __restrict__ m1, float vth)
{
    int which = blockIdx.x >> 9;              // grid 1024: 512 blocks each
    const float* yT = which ? y1 : y0;
    unsigned int* mask = which ? m1 : m0;
    int g = (blockIdx.x & 511) * 256 + threadIdx.x;
    int ch = g & 255;
    int w = (g >> 8) & 63;
    int b = g >> 14;
    float v[32];
#pragma unroll
    for (int j = 0; j < 32; ++j) v[j] = 0.f;
    for (int t = 0; t < TTIME; ++t) {
        int slice = t * BB + b;
        const float* yr = yT + ((size_t)slice * NPOS + w * 32) * C + ch;
        unsigned int mw = 0;
#pragma unroll
        for (int j = 0; j < 32; ++j) {
            float yy = yr[(size_t)j * C];
            float vn = v[j] + (yy - v[j]) * 0.5f;
            int sp = (vn - vth) >= 0.0f;
            mw |= ((unsigned int)sp) << j;
            v[j] = sp ? 0.f : vn;
        }
        mask[((size_t)slice * C + ch) * 64 + w] = mw;
    }
}

// ---------------- kv popcount ----------------
__global__ __launch_bounds__(256) void kv_kern(
    const unsigned int* __restrict__ km_g, const unsigned int* __restrict__ vm_g,
    int* __restrict__ kv_g)
{
    int blk = blockIdx.x;
    int h = blk & 7;
    int tb = blk >> 3;
    __shared__ unsigned int km[32][65], vm[32][65];
    int tid = threadIdx.x;
#pragma unroll
    for (int i = 0; i < 8; ++i) {
        int idx = i * 256 + tid;
        int d = idx >> 6, w = idx & 63;
        size_t rb = ((size_t)tb * C + h * 32 + d) * 64 + w;
        km[d][w] = km_g[rb];
        vm[d][w] = vm_g[rb];
    }
    __syncthreads();
#pragma unroll
    for (int k = 0; k < 4; ++k) {
        int p = k * 256 + tid;
        int d = p >> 5, e = p & 31;
        int s = 0;
#pragma unroll
        for (int w = 0; w < 64; ++w)
            s += __popc(km[d][w] & vm[e][w]);
        kv_g[(size_t)blk * 1024 + p] = s;
    }
}

// ---------------- attention + attn-LIF -> bit mask ----------------
__global__ __launch_bounds__(256) void attn_kern(
    const unsigned int* __restrict__ qm_g, const int* __restrict__ kv_g,
    unsigned int* __restrict__ amask)
{
    int blk = blockIdx.x;
    int chunk = blk & 7;
    int bh = blk >> 3;
    int h = bh & 7, b = bh >> 3;
    int tid = threadIdx.x;
    __shared__ int kvs[1024];
    __shared__ unsigned int qw[32][8];
    float v[32];
#pragma unroll
    for (int e = 0; e < 32; ++e) v[e] = 0.f;
    for (int t = 0; t < TTIME; ++t) {
        int tb = t * BB + b;
        __syncthreads();
#pragma unroll
        for (int k = 0; k < 4; ++k)
            kvs[k * 256 + tid] = kv_g[((size_t)tb * 8 + h) * 1024 + k * 256 + tid];
        {
            int d = tid >> 3, wi = tid & 7;
            qw[d][wi] = qm_g[((size_t)tb * C + h * 32 + d) * 64 + chunk * 8 + wi];
        }
        __syncthreads();
        int a[32];
#pragma unroll
        for (int e = 0; e < 32; ++e) a[e] = 0;
        int wsel = tid >> 5, bitp = tid & 31;
        for (int d = 0; d < 32; ++d) {
            if ((qw[d][wsel] >> bitp) & 1u) {
                const int* kr = &kvs[d * 32];
#pragma unroll
                for (int e = 0; e < 32; ++e) a[e] += kr[e];
            }
        }
#pragma unroll
        for (int e = 0; e < 32; ++e) {
            float f = (float)a[e] * 0.125f;
            v[e] = v[e] + (f - v[e]) * 0.5f;
            int sp = (v[e] - 0.5f) >= 0.0f;
            unsigned long long bb = __ballot(sp);
            if ((tid & 63) == 0) {
                int ch = h * 32 + e;
                unsigned long long* dst = (unsigned long long*)amask
                    + ((size_t)tb * C + ch) * 32 + chunk * 4 + (tid >> 6);
                *dst = bb;
            }
            if (sp) v[e] = 0.f;
        }
    }
}

extern "C" void kernel_launch(void* const* d_in, const int* in_sizes, int n_in,
                              void* d_out, int out_size, void* d_ws, size_t ws_size,
                              hipStream_t stream) {
    const float* q   = (const float*)d_in[0];
    const float* k_  = (const float*)d_in[1];
    const float* w1g = (const float*)d_in[2];
    const float* bn1 = (const float*)d_in[3];
    const float* w3g = (const float*)d_in[4];
    const float* w2g = (const float*)d_in[5];
    const float* bn2 = (const float*)d_in[6];
    const float* bno = (const float*)d_in[7];

    float* prm = (float*)d_ws;                                        // 792576 f32
    unsigned short* frags = (unsigned short*)(prm + 6 * PRM_STRIDE);  // 12*196608 bf16
    float* bufA = (float*)(frags + 12 * FRAG_ELEMS);                  // 16777216 f32
    float* bufB = bufA + 16777216;                                    // 16777216 f32
    unsigned int* qmask = (unsigned int*)(bufB + 16777216);           // 524288 u32 each
    unsigned int* kmask = qmask + 524288;
    unsigned int* vmask = kmask + 524288;
    int* kvb = (int*)(vmask + 524288);                                // 262144 i32
    unsigned int* amask = (unsigned int*)(kvb + 262144);              // 524288 u32
    float* bufC = (float*)(amask + 524288);                           // optional
    float* bufD = bufC + 16777216;                                    // optional

    const size_t BASE_BYTES  = (size_t)((char*)(amask + 524288) - (char*)d_ws);
    const size_t NEED3 = BASE_BYTES + 67108864ull;       // + bufC
    const size_t NEED4 = BASE_BYTES + 2ull * 67108864ull; // + bufC + bufD

    prep_kern<<<6, 256, 0, stream>>>(w1g, bn1, w3g, w2g, bn2, bno, prm);
    prep2_kern<<<12, 256, 0, stream>>>(prm, frags);

#define FRAG(i, which) (frags + (size_t)((i) * 2 + (which)) * FRAG_ELEMS)
#define PRMI(i) (prm + (size_t)(i) * PRM_STRIDE)
#define CA(xx, mm, yy, ii) CArgs{ (xx), (mm), (yy), FRAG(ii, 0), FRAG(ii, 1), PRMI(ii) }

    CArgs nil = CA((const float*)nullptr, (const unsigned int*)nullptr, (float*)nullptr, 0);

    if (ws_size >= NEED4) {
        // fully merged: {conv0,conv1,conv3} then {conv2,conv4}
        conv_fused<0, 1, 3><<<3072, 256, 0, stream>>>(
            CA(q, nullptr, bufA, 0), CA(k_, nullptr, bufB, 1), CA(k_, nullptr, bufC, 3));
        lif_kern<<<512, 256, 0, stream>>>(bufA, qmask, 1.0f);
        conv_fused<1, 1, 2><<<2048, 256, 0, stream>>>(
            CA(bufB, nullptr, bufA, 2), CA(bufC, nullptr, bufD, 4), nil);
        lif2_kern<<<1024, 256, 0, stream>>>(bufA, kmask, bufD, vmask, 1.0f);
    } else if (ws_size >= NEED3) {
        // merged3 only; conv2/conv4 sequential via freed buffers
        conv_fused<0, 1, 3><<<3072, 256, 0, stream>>>(
            CA(q, nullptr, bufA, 0), CA(k_, nullptr, bufB, 1), CA(k_, nullptr, bufC, 3));
        lif_kern<<<512, 256, 0, stream>>>(bufA, qmask, 1.0f);
        conv_fused<1, 1, 1><<<1024, 256, 0, stream>>>(CA(bufB, nullptr, bufA, 2), nil, nil);
        lif_kern<<<512, 256, 0, stream>>>(bufA, kmask, 1.0f);
        conv_fused<1, 1, 1><<<1024, 256, 0, stream>>>(CA(bufC, nullptr, bufA, 4), nil, nil);
        lif_kern<<<512, 256, 0, stream>>>(bufA, vmask, 1.0f);
    } else {
        // R13 sequential fallback (2 big buffers)
        conv_fused<0, 1, 1><<<1024, 256, 0, stream>>>(CA(q, nullptr, bufA, 0), nil, nil);
        lif_kern<<<512, 256, 0, stream>>>(bufA, qmask, 1.0f);
        conv_fused<0, 1, 1><<<1024, 256, 0, stream>>>(CA(k_, nullptr, bufA, 1), nil, nil);
        conv_fused<1, 1, 1><<<1024, 256, 0, stream>>>(CA(bufA, nullptr, bufB, 2), nil, nil);
        lif_kern<<<512, 256, 0, stream>>>(bufB, kmask, 1.0f);
        conv_fused<0, 1, 1><<<1024, 256, 0, stream>>>(CA(k_, nullptr, bufA, 3), nil, nil);
        conv_fused<1, 1, 1><<<1024, 256, 0, stream>>>(CA(bufA, nullptr, bufB, 4), nil, nil);
        lif_kern<<<512, 256, 0, stream>>>(bufB, vmask, 1.0f);
    }

    kv_kern<<<256, 256, 0, stream>>>(kmask, vmask, kvb);
    attn_kern<<<512, 256, 0, stream>>>(qmask, kvb, amask);

    // final conv5: spike-input, standard-layout output
    conv_fused<2, 0, 1><<<1024, 256, 0, stream>>>(
        CArgs{ nullptr, amask, (float*)d_out, FRAG(5, 0), FRAG(5, 1), PRMI(5) }, nil, nil);
}

// Round 16
// 794.195 us; speedup vs baseline: 1.1421x; 1.0102x over previous
//
#include <hip/hip_runtime.h>

#define C 256
#define NPOS 2048
#define BB 8
#define TTIME 4
#define PRM_STRIDE 132096  // w1fT 65536 | w2fT 65536 | w3T 768 | bias 256
#define FRAG_ELEMS 196608  // 8 ks * 16 mt * 3 s * 64 lane * 8 j (bf16)

typedef float f32x4 __attribute__((ext_vector_type(4)));
typedef short short8 __attribute__((ext_vector_type(8)));
typedef unsigned int u32x4 __attribute__((ext_vector_type(4)));

static __device__ __forceinline__ unsigned short f2bf(float f) {
    unsigned int u = __float_as_uint(f);
    return (unsigned short)((u + 0x7FFFu + ((u >> 16) & 1u)) >> 16);
}
static __device__ __forceinline__ float bf2f(unsigned short b) {
    return __uint_as_float(((unsigned int)b) << 16);
}
static __device__ __forceinline__ void split3(float f, unsigned short& h,
                                              unsigned short& m, unsigned short& l) {
    h = f2bf(f);
    float r1 = f - bf2f(h);
    m = f2bf(r1);
    float r2 = r1 - bf2f(m);
    l = f2bf(r2);
}
// truncation-based 3-way split of a PAIR of f32 into packed 2xbf16 words.
static __device__ __forceinline__ void tsplit_pair(float a, float b,
    unsigned int& hp, unsigned int& mp, unsigned int& lp) {
    unsigned int ua = __float_as_uint(a), ub = __float_as_uint(b);
    hp = (ua >> 16) | (ub & 0xFFFF0000u);
    float ra = a - __uint_as_float(ua & 0xFFFF0000u);
    float rb = b - __uint_as_float(ub & 0xFFFF0000u);
    unsigned int ura = __float_as_uint(ra), urb = __float_as_uint(rb);
    mp = (ura >> 16) | (urb & 0xFFFF0000u);
    float sa = ra - __uint_as_float(ura & 0xFFFF0000u);
    float sb = rb - __uint_as_float(urb & 0xFFFF0000u);
    lp = (__float_as_uint(sa) >> 16) | (__float_as_uint(sb) & 0xFFFF0000u);
}

// ---------------- PREP1: fold BN params into conv weights (f32) ----------------
__global__ __launch_bounds__(256) void prep_kern(
    const float* __restrict__ w1g, const float* __restrict__ bn1,
    const float* __restrict__ w3g, const float* __restrict__ w2g,
    const float* __restrict__ bn2, const float* __restrict__ bno,
    float* __restrict__ prm)
{
    int i = blockIdx.x;
    int tid = threadIdx.x;
    __shared__ float s1l[C], hcl[C], SGl[C];
    const float* b1 = bn1 + i * 4 * C;
    const float* b2 = bn2 + i * 4 * C;
    const float* bo = bno + i * 4 * C;
    float g1 = b1[tid], be1 = b1[C + tid], mu1 = b1[2 * C + tid], va1 = b1[3 * C + tid];
    float s1 = g1 / sqrtf(va1 + 1e-5f);
    float h1 = be1 - mu1 * s1;
    float g2 = b2[tid], be2 = b2[C + tid], mu2 = b2[2 * C + tid], va2 = b2[3 * C + tid];
    float s2 = g2 / sqrtf(va2 + 1e-5f);
    float h2 = be2 - mu2 * s2;
    float go = bo[tid], beo = bo[C + tid], muo = bo[2 * C + tid], vao = bo[3 * C + tid];
    float so = go / sqrtf(vao + 1e-5f);
    float ho = beo - muo * so;
    float SG = so * s2;
    float SH = so * h2 + ho;
    const float* w3i = w3g + i * C * 3;
    float w3s = w3i[tid * 3 + 0] + w3i[tid * 3 + 1] + w3i[tid * 3 + 2];
    s1l[tid] = s1; hcl[tid] = w3s * h1; SGl[tid] = SG;
    __syncthreads();
    float* prmi = prm + (size_t)i * PRM_STRIDE;
    const float* w1i = w1g + (size_t)i * C * C;
    const float* w2i = w2g + (size_t)i * C * C;
    for (int k = 0; k < C; ++k)
        prmi[tid * C + k] = s1l[k] * w1i[k * C + tid];
    for (int k = 0; k < C; ++k)
        prmi[65536 + tid * C + k] = SGl[k] * w2i[k * C + tid];
    for (int j = 0; j < 3; ++j)
        prmi[131072 + j * C + tid] = w3i[tid * 3 + j];
    float dot = 0.f;
    for (int k = 0; k < C; ++k)
        dot = fmaf(w2i[tid * C + k], hcl[k], dot);
    prmi[131840 + tid] = SG * dot + SH;
}

// ---------------- PREP2: build bf16x3 MFMA A-fragments ----------------
// frag layout: ((((ks*16 + mt)*3 + s)*64 + lane)*8 + j)
// lane l holds A[m = mt*16 + (l&15)][k = ks*32 + (l>>4)*8 + j]
__global__ __launch_bounds__(256) void prep2_kern(
    const float* __restrict__ prm, unsigned short* __restrict__ frags)
{
    int b = blockIdx.x;           // 12 = 6 convs x 2 matrices
    int i = b >> 1, which = b & 1;
    const float* src = prm + (size_t)i * PRM_STRIDE + which * 65536;  // wT[k*256+m]
    unsigned short* dst = frags + (size_t)b * FRAG_ELEMS;
    for (int e = threadIdx.x; e < 65536; e += 256) {
        int m = e & 255, k = e >> 8;
        float w = src[k * 256 + m];
        unsigned short h, mi, lo;
        split3(w, h, mi, lo);
        int ks = k >> 5, kin = k & 31;
        int mt = m >> 4;
        int lane = (m & 15) | (((kin >> 3) & 3) << 4);
        int j = kin & 7;
        size_t base = ((size_t)(ks * 16 + mt) * 3) * 64 * 8 + lane * 8 + j;
        dst[base] = h;
        dst[base + 512] = mi;
        dst[base + 1024] = lo;
    }
}

// ---------------- FUSED conv: y = W2f * dw3(W1f * x) + bias ----------------
// IN_MODE: 0 = STD f32 [c][pos], 1 = TRS f32 [pos][c], 2 = SPIKE bitmask
// OUT_T:   1 = transposed yT[pos][c] (LDS-staged coalesced), 0 = standard y[c][pos]
// Best-measured structure (R13, 794us): 4 sub-phase both stages, 30720 B LDS,
// (256,2) bounds, tsplit staging.
//   stage 1: x planes 80 cols x 64 k  @ 0/10240/20480  (30720 B, 4 sub-phases)
//   stage 2: t planes 64 cols x 64 k  @ 0/8192/16384   (24576 B, 4 sub-phases)
//   epilogue: 16 pos x 256 c f32      @ 0..16384       (4 phases)
// All acc indices compile-time (rule #20). Spill tripwire: WRITE_SIZE>65536.
template<int IN_MODE, int OUT_T>
__global__ __launch_bounds__(256, 2) void conv_fused(
    const float* __restrict__ x, const unsigned int* __restrict__ xmask,
    float* __restrict__ y, const unsigned short* __restrict__ fragA,
    const unsigned short* __restrict__ fragB, const float* __restrict__ prmi)
{
    __shared__ __align__(16) char lds[30720];
    const int tid = threadIdx.x;
    const int lane = tid & 63, wv = tid >> 6;
    const int ctile = blockIdx.x & 31;
    const int slice = blockIdx.x >> 5;
    const int l0 = ctile * 64;
    const int lo4 = lane & 15, rg = lane >> 4;
    const int PA[6] = {0, 0, 1, 0, 2, 1};
    const int PB[6] = {0, 1, 0, 2, 0, 1};

    int mt[4];
#pragma unroll
    for (int rt = 0; rt < 4; ++rt) mt[rt] = wv + 4 * rt;

    f32x4 acc1[4][5];
#pragma unroll
    for (int a = 0; a < 4; ++a)
#pragma unroll
        for (int b = 0; b < 5; ++b) acc1[a][b] = (f32x4)0.f;

    const short8* Ab1 = (const short8*)fragA;

    // prefetch buffer: 5 units x 4 k-elements
    float LDf[20];
    unsigned int LDu[20];

#define ISSUE(sp_)                                                             \
    {                                                                          \
        _Pragma("unroll")                                                      \
        for (int it = 0; it < 5; ++it) {                                       \
            int u = it * 256 + tid;                                            \
            int col = u % 80;                                                  \
            int kq4 = u / 80;                                                  \
            int gpos = l0 - 8 + col;                                           \
            bool ok = (unsigned)gpos < (unsigned)NPOS;                         \
            int k0 = (sp_) * 64 + kq4 * 4;                                     \
            if (IN_MODE == 2) {                                                \
                const unsigned int* mg = xmask + (size_t)slice * C * 64 + (gpos >> 5); \
                _Pragma("unroll")                                              \
                for (int j = 0; j < 4; ++j)                                    \
                    LDu[it * 4 + j] = ok ? mg[(k0 + j) * 64] : 0u;             \
            } else if (IN_MODE == 0) {                                         \
                const float* xg = x + (size_t)slice * C * NPOS + gpos;         \
                _Pragma("unroll")                                              \
                for (int j = 0; j < 4; ++j)                                    \
                    LDf[it * 4 + j] = ok ? xg[(size_t)(k0 + j) * NPOS] : 0.f;  \
            } else {                                                           \
                if (ok) {                                                      \
                    float4 a4 = *(const float4*)(x + ((size_t)slice * NPOS + gpos) * C + k0); \
                    LDf[it * 4 + 0] = a4.x; LDf[it * 4 + 1] = a4.y;            \
                    LDf[it * 4 + 2] = a4.z; LDf[it * 4 + 3] = a4.w;            \
                } else {                                                       \
                    _Pragma("unroll")                                          \
                    for (int j = 0; j < 4; ++j) LDf[it * 4 + j] = 0.f;         \
                }                                                              \
            }                                                                  \
        }                                                                      \
    }

#define SPLIT(sp_)                                                             \
    {                                                                          \
        _Pragma("unroll")                                                      \
        for (int it = 0; it < 5; ++it) {                                       \
            int u = it * 256 + tid;                                            \
            int col = u % 80;                                                  \
            int kq4 = u / 80;                                                  \
            int base = col * 128 + ((((kq4 >> 1) ^ (col & 7)) & 7) << 4) + (kq4 & 1) * 8; \
            if (IN_MODE == 2) {                                                \
                int gpos = l0 - 8 + col;                                       \
                int bitp = gpos & 31;                                          \
                unsigned int h01 = (((LDu[it * 4 + 0] >> bitp) & 1u) ? 0x3F80u : 0u)   \
                                 | (((LDu[it * 4 + 1] >> bitp) & 1u) ? 0x3F800000u : 0u); \
                unsigned int h23 = (((LDu[it * 4 + 2] >> bitp) & 1u) ? 0x3F80u : 0u)   \
                                 | (((LDu[it * 4 + 3] >> bitp) & 1u) ? 0x3F800000u : 0u); \
                *(unsigned long long*)(lds + base) =                           \
                    (unsigned long long)h01 | ((unsigned long long)h23 << 32); \
            } else {                                                           \
                unsigned int h01, m01, l01, h23, m23, l23;                     \
                tsplit_pair(LDf[it * 4 + 0], LDf[it * 4 + 1], h01, m01, l01);  \
                tsplit_pair(LDf[it * 4 + 2], LDf[it * 4 + 3], h23, m23, l23);  \
                *(unsigned long long*)(lds + base) =                           \
                    (unsigned long long)h01 | ((unsigned long long)h23 << 32); \
                *(unsigned long long*)(lds + 10240 + base) =                   \
                    (unsigned long long)m01 | ((unsigned long long)m23 << 32); \
                *(unsigned long long*)(lds + 20480 + base) =                   \
                    (unsigned long long)l01 | ((unsigned long long)l23 << 32); \
            }                                                                  \
        }                                                                      \
    }

    // ================= STAGE 1: u = W1f * x (4 pipelined 64-k sub-phases) ====
    ISSUE(0);
#pragma unroll
    for (int sp = 0; sp < 4; ++sp) {
        SPLIT(sp);
        if (sp < 3) ISSUE(sp + 1);
        __syncthreads();
#pragma unroll
        for (int ksl = 0; ksl < 2; ++ksl) {
            int ks = sp * 2 + ksl;
            int oct = ksl * 4 + rg;          // 0..7
            short8 A[4][3];
#pragma unroll
            for (int rt = 0; rt < 4; ++rt)
#pragma unroll
                for (int s = 0; s < 3; ++s)
                    A[rt][s] = Ab1[(size_t)((ks * 16 + mt[rt]) * 3 + s) * 64 + lane];
            int ba[5];
#pragma unroll
            for (int ct = 0; ct < 5; ++ct) {
                int colb = ct * 16 + lo4;
                ba[ct] = colb * 128 + (((oct ^ (colb & 7)) & 7) << 4);
            }
            if (IN_MODE == 2) {
                short8 B[5];
#pragma unroll
                for (int ct = 0; ct < 5; ++ct)
                    B[ct] = *(const short8*)(lds + ba[ct]);
                __builtin_amdgcn_s_setprio(1);
#pragma unroll
                for (int pp = 0; pp < 3; ++pp)
#pragma unroll
                    for (int rt = 0; rt < 4; ++rt)
#pragma unroll
                        for (int ct = 0; ct < 5; ++ct)
                            acc1[rt][ct] = __builtin_amdgcn_mfma_f32_16x16x32_bf16(
                                A[rt][pp], B[ct], acc1[rt][ct], 0, 0, 0);
                __builtin_amdgcn_s_setprio(0);
            } else {
                short8 B[5][3];
#pragma unroll
                for (int ct = 0; ct < 5; ++ct) {
                    B[ct][0] = *(const short8*)(lds + ba[ct]);
                    B[ct][1] = *(const short8*)(lds + 10240 + ba[ct]);
                    B[ct][2] = *(const short8*)(lds + 20480 + ba[ct]);
                }
                __builtin_amdgcn_s_setprio(1);
#pragma unroll
                for (int pp = 0; pp < 6; ++pp)
#pragma unroll
                    for (int rt = 0; rt < 4; ++rt)
#pragma unroll
                        for (int ct = 0; ct < 5; ++ct)
                            acc1[rt][ct] = __builtin_amdgcn_mfma_f32_16x16x32_bf16(
                                A[rt][PA[pp]], B[ct][PB[pp]], acc1[rt][ct], 0, 0, 0);
                __builtin_amdgcn_s_setprio(0);
            }
        }
        __syncthreads();
    }

    // ================= STAGE 2: y = W2f * dw3(u), 4 sub-phases of 64 k' ======
    const float* w3p = prmi + 131072;
    const short8* Ab2 = (const short8*)fragB;
    f32x4 acc2[4][4];
#pragma unroll
    for (int a = 0; a < 4; ++a)
#pragma unroll
        for (int b = 0; b < 4; ++b) acc2[a][b] = (f32x4)0.f;

#pragma unroll
    for (int s = 0; s < 4; ++s) {
        // ---- depthwise (register shuffles) + trunc-split + t-plane write: rt = s ----
        {
            const int rt = s;                // compile-time after unroll
            int RTB = mt[rt] << 4;           // (wv + 4s)*16 -> k' in [64s,64s+64)
            float w3a[4], w3b[4], w3c[4];
#pragma unroll
            for (int r = 0; r < 4; ++r) {
                int m = RTB + rg * 4 + r;
                w3a[r] = w3p[m]; w3b[r] = w3p[256 + m]; w3c[r] = w3p[512 + m];
            }
            int k0 = (RTB & 63) + rg * 4;    // wv*16 + rg*4, within [0,64)
#pragma unroll
            for (int ct = 0; ct < 5; ++ct) {
                int sc = ct * 16 + lo4;
                float tv[4];
#pragma unroll
                for (int r = 0; r < 4; ++r) {
                    float cur = acc1[rt][ct][r];
                    float prevv = acc1[rt][ct > 0 ? ct - 1 : 0][r];
                    float nextv = acc1[rt][ct < 4 ? ct + 1 : 4][r];
                    float sL  = __shfl(cur, lane - 1);
                    float sL2 = __shfl(prevv, lane + 15);
                    float sR  = __shfl(cur, lane + 1);
                    float sR2 = __shfl(nextv, lane - 15);
                    float uL = lo4 ? sL : sL2;
                    float uR = (lo4 == 15) ? sR2 : sR;
                    tv[r] = w3a[r] * uL + w3b[r] * cur + w3c[r] * uR;
                }
                if (sc >= 8 && sc < 72) {
                    int oc = sc - 8;
                    int base = oc * 128 + ((((k0 >> 3) ^ (oc & 7)) & 7) << 4) + (k0 & 7) * 2;
                    unsigned int h01, m01, l01, h23, m23, l23;
                    tsplit_pair(tv[0], tv[1], h01, m01, l01);
                    tsplit_pair(tv[2], tv[3], h23, m23, l23);
                    *(unsigned long long*)(lds + base) =
                        (unsigned long long)h01 | ((unsigned long long)h23 << 32);
                    *(unsigned long long*)(lds + 8192 + base) =
                        (unsigned long long)m01 | ((unsigned long long)m23 << 32);
                    *(unsigned long long*)(lds + 16384 + base) =
                        (unsigned long long)l01 | ((unsigned long long)l23 << 32);
                }
            }
        }
        __syncthreads();
        // ---- MFMA: ks = 2s, 2s+1 over all rt, ct ----
#pragma unroll
        for (int ksl = 0; ksl < 2; ++ksl) {
            int ks = s * 2 + ksl;
            int chunk = ksl * 4 + rg;        // 0..7
            short8 A[4][3];
#pragma unroll
            for (int rt = 0; rt < 4; ++rt)
#pragma unroll
                for (int ss = 0; ss < 3; ++ss)
                    A[rt][ss] = Ab2[(size_t)((ks * 16 + mt[rt]) * 3 + ss) * 64 + lane];
            short8 B[4][3];
#pragma unroll
            for (int ct = 0; ct < 4; ++ct) {
                int oc = ct * 16 + lo4;
                int ba = oc * 128 + (((chunk ^ (oc & 7)) & 7) << 4);
                B[ct][0] = *(const short8*)(lds + ba);
                B[ct][1] = *(const short8*)(lds + 8192 + ba);
                B[ct][2] = *(const short8*)(lds + 16384 + ba);
            }
            __builtin_amdgcn_s_setprio(1);
#pragma unroll
            for (int pp = 0; pp < 6; ++pp)
#pragma unroll
                for (int rt = 0; rt < 4; ++rt)
#pragma unroll
                    for (int ct = 0; ct < 4; ++ct)
                        acc2[rt][ct] = __builtin_amdgcn_mfma_f32_16x16x32_bf16(
                            A[rt][PA[pp]], B[ct][PB[pp]], acc2[rt][ct], 0, 0, 0);
            __builtin_amdgcn_s_setprio(0);
        }
        __syncthreads();
    }

    // ================= epilogue =================
    const float* bs = prmi + 131840;
    float* yS = y + (size_t)slice * NPOS * C;
    if (OUT_T) {
        // LDS-staged transpose: 4 phases of 16 pos x 256 ch (16 KB), then
        // fully-coalesced 1KB-per-wave row stores.
#pragma unroll
        for (int ph = 0; ph < 4; ++ph) {
            if (ph) __syncthreads();
#pragma unroll
            for (int rt = 0; rt < 4; ++rt) {
                int m0 = (mt[rt] << 4) + rg * 4;
                int chunk = (mt[rt] << 2) + rg;       // m0/4, 0..63
                int cl = lo4;                         // 0..15
                f32x4 o;
#pragma unroll
                for (int r = 0; r < 4; ++r) o[r] = acc2[rt][ph][r] + bs[m0 + r];
                *(f32x4*)(lds + cl * 1024 + ((chunk ^ (cl & 7)) << 4)) = o;
            }
            __syncthreads();
#pragma unroll
            for (int i = 0; i < 4; ++i) {
                int u = i * 256 + tid;                // 1024 units of 16B
                int cl = u >> 6, cchunk = u & 63;
                f32x4 o = *(const f32x4*)(lds + cl * 1024 + ((cchunk ^ (cl & 7)) << 4));
                int pos = l0 + ph * 16 + cl;
                *(f32x4*)(yS + (size_t)pos * C + cchunk * 4) = o;
            }
        }
    } else {
#pragma unroll
        for (int rt = 0; rt < 4; ++rt) {
            int m0 = (mt[rt] << 4) + rg * 4;
#pragma unroll
            for (int ct = 0; ct < 4; ++ct) {
                int pos = l0 + ct * 16 + lo4;
#pragma unroll
                for (int r = 0; r < 4; ++r)
                    yS[(size_t)(m0 + r) * NPOS + pos] = acc2[rt][ct][r] + bs[m0 + r];
            }
        }
    }
#undef ISSUE
#undef SPLIT
}

// ---------------- LIF + bitpack over T timesteps (reads yT[pos][c]) ----------------
__global__ __launch_bounds__(256) void lif_kern(
    const float* __restrict__ yT, unsigned int* __restrict__ mask, float vth)
{
    int g = blockIdx.x * 256 + threadIdx.x;   // 131072 = 8b x 64w x 256ch
    int ch = g & 255;
    int w = (g >> 8) & 63;
    int b = g >> 14;
    float v[32];
#pragma unroll
    for (int j = 0; j < 32; ++j) v[j] = 0.f;
    for (int t = 0; t < TTIME; ++t) {
        int slice = t * BB + b;
        const float* yr = yT + ((size_t)slice * NPOS + w * 32) * C + ch;
        unsigned int mw = 0;
#pragma unroll
        for (int j = 0; j < 32; ++j) {
            float yy = yr[(size_t)j * C];
            float vn = v[j] + (yy - v[j]) * 0.5f;
            int sp = (vn - vth) >= 0.0f;
            mw |= ((unsigned int)sp) << j;
            v[j] = sp ? 0.f : vn;
        }
        mask[((size_t)slice * C + ch) * 64 + w] = mw;
    }
}

// ---------------- kv popcount ----------------
__global__ __launch_bounds__(256) void kv_kern(
    const unsigned int* __restrict__ km_g, const unsigned int* __restrict__ vm_g,
    int* __restrict__ kv_g)
{
    int blk = blockIdx.x;
    int h = blk & 7;
    int tb = blk >> 3;
    __shared__ unsigned int km[32][65], vm[32][65];
    int tid = threadIdx.x;
#pragma unroll
    for (int i = 0; i < 8; ++i) {
        int idx = i * 256 + tid;
        int d = idx >> 6, w = idx & 63;
        size_t rb = ((size_t)tb * C + h * 32 + d) * 64 + w;
        km[d][w] = km_g[rb];
        vm[d][w] = vm_g[rb];
    }
    __syncthreads();
#pragma unroll
    for (int k = 0; k < 4; ++k) {
        int p = k * 256 + tid;
        int d = p >> 5, e = p & 31;
        int s = 0;
#pragma unroll
        for (int w = 0; w < 64; ++w)
            s += __popc(km[d][w] & vm[e][w]);
        kv_g[(size_t)blk * 1024 + p] = s;
    }
}

// ---------------- attention + attn-LIF -> bit mask ----------------
__global__ __launch_bounds__(256) void attn_kern(
    const unsigned int* __restrict__ qm_g, const int* __restrict__ kv_g,
    unsigned int* __restrict__ amask)
{
    int blk = blockIdx.x;
    int chunk = blk & 7;
    int bh = blk >> 3;
    int h = bh & 7, b = bh >> 3;
    int tid = threadIdx.x;
    __shared__ int kvs[1024];
    __shared__ unsigned int qw[32][8];
    float v[32];
#pragma unroll
    for (int e = 0; e < 32; ++e) v[e] = 0.f;
    for (int t = 0; t < TTIME; ++t) {
        int tb = t * BB + b;
        __syncthreads();
#pragma unroll
        for (int k = 0; k < 4; ++k)
            kvs[k * 256 + tid] = kv_g[((size_t)tb * 8 + h) * 1024 + k * 256 + tid];
        {
            int d = tid >> 3, wi = tid & 7;
            qw[d][wi] = qm_g[((size_t)tb * C + h * 32 + d) * 64 + chunk * 8 + wi];
        }
        __syncthreads();
        int a[32];
#pragma unroll
        for (int e = 0; e < 32; ++e) a[e] = 0;
        int wsel = tid >> 5, bitp = tid & 31;
        for (int d = 0; d < 32; ++d) {
            if ((qw[d][wsel] >> bitp) & 1u) {
                const int* kr = &kvs[d * 32];
#pragma unroll
                for (int e = 0; e < 32; ++e) a[e] += kr[e];
            }
        }
#pragma unroll
        for (int e = 0; e < 32; ++e) {
            float f = (float)a[e] * 0.125f;
            v[e] = v[e] + (f - v[e]) * 0.5f;
            int sp = (v[e] - 0.5f) >= 0.0f;
            unsigned long long bb = __ballot(sp);
            if ((tid & 63) == 0) {
                int ch = h * 32 + e;
                unsigned long long* dst = (unsigned long long*)amask
                    + ((size_t)tb * C + ch) * 32 + chunk * 4 + (tid >> 6);
                *dst = bb;
            }
            if (sp) v[e] = 0.f;
        }
    }
}

extern "C" void kernel_launch(void* const* d_in, const int* in_sizes, int n_in,
                              void* d_out, int out_size, void* d_ws, size_t ws_size,
                              hipStream_t stream) {
    const float* q   = (const float*)d_in[0];
    const float* k_  = (const float*)d_in[1];
    const float* w1g = (const float*)d_in[2];
    const float* bn1 = (const float*)d_in[3];
    const float* w3g = (const float*)d_in[4];
    const float* w2g = (const float*)d_in[5];
    const float* bn2 = (const float*)d_in[6];
    const float* bno = (const float*)d_in[7];

    float* prm = (float*)d_ws;                                        // 792576 f32
    unsigned short* frags = (unsigned short*)(prm + 6 * PRM_STRIDE);  // 12*196608 bf16
    float* bufA = (float*)(frags + 12 * FRAG_ELEMS);                  // 16777216 f32
    float* bufB = bufA + 16777216;                                    // 16777216 f32
    unsigned int* qmask = (unsigned int*)(bufB + 16777216);           // 524288 u32 each
    unsigned int* kmask = qmask + 524288;
    unsigned int* vmask = kmask + 524288;
    int* kvb = (int*)(vmask + 524288);                                // 262144 i32
    unsigned int* amask = (unsigned int*)(kvb + 262144);              // 524288 u32

    prep_kern<<<6, 256, 0, stream>>>(w1g, bn1, w3g, w2g, bn2, bno, prm);
    prep2_kern<<<12, 256, 0, stream>>>(prm, frags);

#define FRAG(i, which) (frags + (size_t)((i) * 2 + (which)) * FRAG_ELEMS)
#define PRMI(i) (prm + (size_t)(i) * PRM_STRIDE)

    // q branch: conv0 -> LIF -> qmask
    conv_fused<0, 1><<<1024, 256, 0, stream>>>(q, nullptr, bufA, FRAG(0, 0), FRAG(0, 1), PRMI(0));
    lif_kern<<<512, 256, 0, stream>>>(bufA, qmask, 1.0f);
    // k branch: conv1 -> conv2 -> LIF -> kmask
    conv_fused<0, 1><<<1024, 256, 0, stream>>>(k_, nullptr, bufA, FRAG(1, 0), FRAG(1, 1), PRMI(1));
    conv_fused<1, 1><<<1024, 256, 0, stream>>>(bufA, nullptr, bufB, FRAG(2, 0), FRAG(2, 1), PRMI(2));
    lif_kern<<<512, 256, 0, stream>>>(bufB, kmask, 1.0f);
    // v branch: conv3 -> conv4 -> LIF -> vmask
    conv_fused<0, 1><<<1024, 256, 0, stream>>>(k_, nullptr, bufA, FRAG(3, 0), FRAG(3, 1), PRMI(3));
    conv_fused<1, 1><<<1024, 256, 0, stream>>>(bufA, nullptr, bufB, FRAG(4, 0), FRAG(4, 1), PRMI(4));
    lif_kern<<<512, 256, 0, stream>>>(bufB, vmask, 1.0f);

    kv_kern<<<256, 256, 0, stream>>>(kmask, vmask, kvb);
    attn_kern<<<512, 256, 0, stream>>>(qmask, kvb, amask);

    // final conv5: spike-input, standard-layout output
    conv_fused<2, 0><<<1024, 256, 0, stream>>>(nullptr, amask, (float*)d_out, FRAG(5, 0), FRAG(5, 1), PRMI(5));
}